// Round 1
// 211.039 us; speedup vs baseline: 1.0568x; 1.0568x over previous
//
#include <hip/hip_runtime.h>
#include <hip/hip_bf16.h>
#include <stdint.h>
#include <stddef.h>

#define D_MODEL 2048
#define NOUT    2048      // SLOTS * D_FIELD
#define BATCH   2
#define SEQ     4096
#define M_TOTAL (BATCH*SEQ)   // 8192
#define SLOTS   8
#define D_FIELD 256
#define CHUNK   32            // scan chunk (was 64): 2x TLP, half the serial chain
#define NCHUNK  (SEQ/CHUNK)   // 128
#define NT      (D_MODEL/64)  // 32 K-tiles of BK=64

typedef __attribute__((ext_vector_type(4))) float  floatx4;
typedef __attribute__((ext_vector_type(8))) __bf16 bf16x8;
typedef __attribute__((ext_vector_type(4))) __bf16 bf16x4;

// ---------------------------------------------------------------------------
// async global -> LDS, 16B per lane. LDS dest must be wave-uniform base + lane*16.
__device__ __forceinline__ void async_copy16(const void* gsrc, void* ldst) {
  __builtin_amdgcn_global_load_lds(
      (__attribute__((address_space(1))) const void*)(uintptr_t)gsrc,
      (__attribute__((address_space(3))) void*)(uintptr_t)ldst,
      16, 0, 0);
}

// ---------------------------------------------------------------------------
// Kernel 1: cast x and W fp32 -> bf16 into workspace. 4 elems / thread. (unchanged)
__global__ void cast_kernel(const float* __restrict__ x,
                            const float* __restrict__ W,
                            __bf16* __restrict__ xb,
                            __bf16* __restrict__ wb) {
  const long long nx = (long long)M_TOTAL * D_MODEL;  // 16777216
  const long long nw = (long long)NOUT * D_MODEL;     // 4194304
  long long base = ((long long)blockIdx.x * blockDim.x + threadIdx.x) * 4;
  if (base < nx) {
    float4 v = *(const float4*)(x + base);
    bf16x4 o;
    o[0] = (__bf16)v.x; o[1] = (__bf16)v.y; o[2] = (__bf16)v.z; o[3] = (__bf16)v.w;
    *(bf16x4*)(xb + base) = o;
  } else {
    long long j = base - nx;
    if (j < nw) {
      float4 v = *(const float4*)(W + j);
      bf16x4 o;
      o[0] = (__bf16)v.x; o[1] = (__bf16)v.y; o[2] = (__bf16)v.z; o[3] = (__bf16)v.w;
      *(bf16x4*)(wb + j) = o;
    }
  }
}

// ---------------------------------------------------------------------------
// Kernel 2: 256x256 8-phase GEMM (T2+T3+T4+T5) + fused per-32-chunk carries.
//
// Geometry: BM=BN=256, BK=64, 512 thr = 8 waves (2M x 4N), wave tile 128x64,
//           acc = 8x4 fragments of 16x16x32 bf16 MFMA. Grid (32,8), 1 block/CU.
// LDS 128KiB: A buf0 @0, A buf1 @32K, B buf0 @64K, B buf1 @96K (each 256x64 bf16).
// Layout: subtile-packed [sr=row/16][sc=col/32] 1024B subtiles, inner [16][32],
//         read-side swizzle byte ^= ((byte>>9)&1)<<5  (bit9 == (row&15)>>3).
// Staging: one gload_lds stages exactly one 1024B subtile (64 lanes x 16B,
//          linear dest); the XOR is applied by PRE-SWIZZLING the global source:
//          lane l -> row (l>>2), colOff ((l&3)*8)^((l>>5)*16).  Round-trip
//          verified: read of (r,k) returns element (r,k).
// Stage units (match per-phase read sets):
//   A-u0 = subtile-rows {0-3,8-11}   (read at tp0: rows wM*128+[0,63])
//   A-u1 = subtile-rows {4-7,12-15}  (read at tp2)
//   B-u0 = subtile-rows {0,1,4,5,8,9,12,13}   (read at tp0: cols wN*64+[0,31])
//   B-u1 = subtile-rows {2,3,6,7,10,11,14,15} (read at tp1)
// Per K-tile T (4 phases), staging tile T+1 into buf^1:
//   tp0: rd A[M0](8)+B[N0](4); stage A-u0'; vmcnt(4); bar; lgkm0; 16 MFMA Q(M0,N0)
//   tp1: rd B[N1](4);          stage B-u0'; vmcnt(4); bar; lgkm0; 16 MFMA Q(M0,N1)
//   tp2: rd A[M1](8);          stage B-u1';           bar; lgkm0; 16 MFMA Q(M1,N1)
//   tp3:                       stage A-u1'; vmcnt(4); bar;        16 MFMA Q(M1,N0)
// vmcnt(4) certification (per-wave queue, 2 loads/stage): the wait at each point
// leaves exactly the 2 newest stage-units outstanding; the unit read next phase
// is always older -> certified. Last tile: no stage, waits tighten to 2,0.
// ---------------------------------------------------------------------------
#define VMW4 asm volatile("s_waitcnt vmcnt(4)" ::: "memory")
#define VMW2 asm volatile("s_waitcnt vmcnt(2)" ::: "memory")
#define VMW0 asm volatile("s_waitcnt vmcnt(0)" ::: "memory")
#define LGKM0 do{ asm volatile("s_waitcnt lgkmcnt(0)" ::: "memory"); \
                  __builtin_amdgcn_sched_barrier(0); }while(0)
#define BAR do{ __builtin_amdgcn_s_barrier(); __builtin_amdgcn_sched_barrier(0); }while(0)

#define DSRD(off) (*(const bf16x8*)(smem + (off)))

#define STG(GP, ROFF, DSTOFF, KTN) do{ \
  async_copy16((GP) + (ROFF) + (KTN)*64,      smem + (DSTOFF)); \
  async_copy16((GP) + (ROFF) + (KTN)*64 + 32, smem + (DSTOFF) + 1024); }while(0)

#define RD_AF(BUF, MOFF) do{ \
  _Pragma("unroll") for (int i_ = 0; i_ < 4; ++i_){ \
  _Pragma("unroll") for (int k_ = 0; k_ < 2; ++k_){ \
    afr[i_][k_] = DSRD((BUF)*32768 + ((wM8+(MOFF)+i_)*2+k_)*1024 + fragOff); }} }while(0)

#define RD_BF(BUF, NOFF, DST) do{ \
  _Pragma("unroll") for (int j_ = 0; j_ < 2; ++j_){ \
  _Pragma("unroll") for (int k_ = 0; k_ < 2; ++k_){ \
    DST[j_][k_] = DSRD(65536 + (BUF)*32768 + ((wN4+(NOFF)+j_)*2+k_)*1024 + fragOff); }} }while(0)

#define MFMA_Q(AM, AN, BFR) do{ \
  __builtin_amdgcn_s_setprio(1); \
  _Pragma("unroll") for (int i_ = 0; i_ < 4; ++i_){ \
  _Pragma("unroll") for (int j_ = 0; j_ < 2; ++j_){ \
  _Pragma("unroll") for (int k_ = 0; k_ < 2; ++k_){ \
    acc[(AM)+i_][(AN)+j_] = __builtin_amdgcn_mfma_f32_16x16x32_bf16( \
        afr[i_][k_], BFR[j_][k_], acc[(AM)+i_][(AN)+j_], 0, 0, 0); }}} \
  __builtin_amdgcn_s_setprio(0); }while(0)

#define KTILE(BUF, KTN, DO_STG) do{ \
  /* tp0 */ \
  RD_AF(BUF, 0); \
  RD_BF(BUF, 0, bfr0); \
  if (DO_STG) STG(gA, rA0, ((BUF)^1)*32768 + dA0, KTN); \
  if (DO_STG) { VMW4; } else { VMW2; } \
  BAR; LGKM0; \
  MFMA_Q(0, 0, bfr0); \
  /* tp1 */ \
  RD_BF(BUF, 2, bfr1); \
  if (DO_STG) STG(gB, rB0, ((BUF)^1)*32768 + dB0, KTN); \
  if (DO_STG) { VMW4; } else { VMW0; } \
  BAR; LGKM0; \
  MFMA_Q(0, 2, bfr1); \
  /* tp2 */ \
  RD_AF(BUF, 4); \
  if (DO_STG) STG(gB, rB1, ((BUF)^1)*32768 + dB1, KTN); \
  BAR; LGKM0; \
  MFMA_Q(4, 2, bfr1); \
  /* tp3 */ \
  if (DO_STG) { STG(gA, rA1, ((BUF)^1)*32768 + dA1, KTN); VMW4; } \
  BAR; \
  MFMA_Q(4, 0, bfr0); \
}while(0)

__global__ __launch_bounds__(512, 2) void gemm_scan_kernel(
    const __bf16* __restrict__ A,    // [M_TOTAL, D_MODEL] bf16
    const __bf16* __restrict__ Bw,   // [NOUT, D_MODEL] bf16
    const float*  __restrict__ bias,
    const float*  __restrict__ alphas,
    float* __restrict__ C,           // [M_TOTAL, NOUT]
    float* __restrict__ carry) {     // [BATCH, NCHUNK, NOUT] per-32-chunk carries
  extern __shared__ __align__(16) char smem[];
  const int t    = threadIdx.x;
  const int lane = t & 63;
  const int w    = t >> 6;        // wave 0..7
  const int wM   = w >> 2;        // 0..1
  const int wN   = w & 3;         // 0..3
  const int m0   = blockIdx.x * 256;   // m fast -> A-panel's 8 n-blocks on one XCD
  const int n0   = blockIdx.y * 256;

  // fragment ds_read addressing (A and B identical roles: lane lr=row, lq=kgrp)
  const int lq = lane >> 4, lr = lane & 15;
  const int fragOff = (lr*64 + lq*16) ^ (((lr >> 3) & 1) << 5);
  const int wM8 = wM*8, wN4 = wN*4;

  // staging: lane -> (row l>>2, pre-swizzled colOff) inside a 16x32 subtile
  const int lrow = lane >> 2;
  const int lcol = ((lane & 3) * 8) ^ ((lane >> 5) * 16);
  const int srA0 = (w & 3) + ((w >> 2) << 3), srA1 = srA0 + 4;       // {0-3,8-11}, {4-7,12-15}
  const int srB0 = (w & 1) + ((w >> 1) << 2), srB1 = srB0 + 2;       // {0,1,4,5,..}, {2,3,6,7,..}
  const __bf16* gA = A  + (size_t)m0 * D_MODEL + lcol;
  const __bf16* gB = Bw + (size_t)n0 * D_MODEL + lcol;
  const int rA0 = (srA0*16 + lrow) * D_MODEL;
  const int rA1 = (srA1*16 + lrow) * D_MODEL;
  const int rB0 = (srB0*16 + lrow) * D_MODEL;
  const int rB1 = (srB1*16 + lrow) * D_MODEL;
  const int dA0 = srA0*2048 + lane*16;            // + buf*32768
  const int dA1 = srA1*2048 + lane*16;
  const int dB0 = 65536 + srB0*2048 + lane*16;
  const int dB1 = 65536 + srB1*2048 + lane*16;

  floatx4 acc[8][4] = {};
  bf16x8 afr[4][2], bfr0[2][2], bfr1[2][2];

  // prologue: stage tile 0 into buf0 in certification order {A-u0,B-u0,B-u1,A-u1}
  STG(gA, rA0, dA0, 0);
  STG(gB, rB0, dB0, 0);
  STG(gB, rB1, dB1, 0);
  STG(gA, rA1, dA1, 0);
  VMW4;                       // A-u0,B-u0 resident; B-u1,A-u1 may be in flight
  BAR;

#pragma unroll 1
  for (int p = 0; p < 15; ++p) {       // tiles 0..29
    KTILE(0, 2*p+1, true);
    KTILE(1, 2*p+2, true);
  }
  KTILE(0, 31, true);                  // tile 30, stages tile 31
  KTILE(1, 0, false);                  // tile 31, drain (waits 2,0)

  // ---- epilogue: C (+bias) and fused per-32-row chunk carries ----
  // C/D: col = lr, row = lq*4 + reg. Wave rows = 4 chunks of 32 (frag pairs).
  const int mW0 = m0 + wM*128;
  const int nW0 = n0 + wN*64;
  const float alpha = alphas[nW0 >> 8];
  const float a2 = alpha*alpha;
  const float a4 = a2*a2;
  const float a8 = a4*a4;
  const float a16 = a8*a8;
  float aq = 1.f;                      // alpha^(12-4q)
#pragma unroll
  for (int i = 0; i < 3; ++i) if (i < 3 - lq) aq *= a4;
  const int bb = mW0 >> 12;            // / SEQ
  const int j0 = (mW0 & (SEQ - 1)) >> 5;   // first 32-chunk of this wave

#pragma unroll
  for (int nf = 0; nf < 4; ++nf) {
    const int n = nW0 + nf*16 + lr;
    const float bv = bias[n];
    float tm[8];
#pragma unroll
    for (int mf = 0; mf < 8; ++mf) {
      const int m = mW0 + mf*16 + lq*4;
      const float u0 = acc[mf][nf][0] + bv;
      const float u1 = acc[mf][nf][1] + bv;
      const float u2 = acc[mf][nf][2] + bv;
      const float u3 = acc[mf][nf][3] + bv;
      C[(size_t)(m+0)*NOUT + n] = u0;
      C[(size_t)(m+1)*NOUT + n] = u1;
      C[(size_t)(m+2)*NOUT + n] = u2;
      C[(size_t)(m+3)*NOUT + n] = u3;
      tm[mf] = ((u0*alpha + u1)*alpha + u2)*alpha + u3;   // rows q*4+{0..3}, exp 3-r
    }
#pragma unroll
    for (int c = 0; c < 4; ++c) {
      // chunk c = frags {2c,2c+1}: carry = sum u * alpha^(31-row)
      float s = (tm[2*c]*a16 + tm[2*c+1]) * aq;
      s += __shfl_xor(s, 16, 64);
      s += __shfl_xor(s, 32, 64);
      if (lq == 0)
        carry[((size_t)bb*NCHUNK + j0 + c)*NOUT + n] = s;
    }
  }
}

// ---------------------------------------------------------------------------
// Kernel 3: self-scanning apply, CHUNK=32. 2048 blocks -> 8 waves/SIMD (2x TLP),
// 32-step serial chain (half of before). Prologue Horner over raw chunk carries
// (L2-resident 2MB buffer, addresses independent of the chain -> pipelined).
__global__ void scan_apply(float* __restrict__ U,
                           const float* __restrict__ alphas,
                           const float* __restrict__ carry) {
  const int idx  = blockIdx.x * blockDim.x + threadIdx.x;  // [0, 2*128*2048)
  const int c    = idx & (NOUT - 1);
  const int rest = idx >> 11;
  const int j    = rest & (NCHUNK - 1);
  const int b    = rest >> 7;
  const float alpha = alphas[c >> 8];
  float aC = alpha;
#pragma unroll
  for (int i = 0; i < 5; ++i) aC *= aC;   // alpha^32

  const float* cb = carry + (size_t)b * NCHUNK * NOUT + c;
  float s = 0.f;
#pragma unroll 8
  for (int jp = 0; jp < j; ++jp)
    s = aC * s + cb[(size_t)jp * NOUT];

  float* p = U + ((size_t)(b * SEQ + j * CHUNK) * NOUT) + c;
#pragma unroll 8
  for (int tt = 0; tt < CHUNK; ++tt) {
    const float v = alpha * s + p[(size_t)tt * NOUT];
    p[(size_t)tt * NOUT] = v;
    s = v;
  }
}

// ---------------------------------------------------------------------------
extern "C" void kernel_launch(void* const* d_in, const int* in_sizes, int n_in,
                              void* d_out, int out_size, void* d_ws, size_t ws_size,
                              hipStream_t stream) {
  const float* x      = (const float*)d_in[0];
  const float* W      = (const float*)d_in[1];
  const float* bias   = (const float*)d_in[2];
  const float* alphas = (const float*)d_in[3];
  float* out = (float*)d_out;

  // workspace layout (bytes): xb 33,554,432 | wb 8,388,608 | carry 2,097,152
  __bf16* xb   = (__bf16*)d_ws;
  __bf16* wb   = (__bf16*)((char*)d_ws + (size_t)M_TOTAL * D_MODEL * 2);
  float* carry = (float*)((char*)d_ws + (size_t)M_TOTAL * D_MODEL * 2
                                       + (size_t)NOUT * D_MODEL * 2);

  // 1) cast fp32 -> bf16
  {
    const long long total = ((long long)M_TOTAL * D_MODEL + (long long)NOUT * D_MODEL) / 4;
    const int blocks = (int)((total + 255) / 256);  // 20480
    cast_kernel<<<blocks, 256, 0, stream>>>(x, W, xb, wb);
  }
  // 2) 256x256 8-phase GEMM + bias -> d_out, fused per-32-chunk carries -> ws
  {
    dim3 grid(M_TOTAL / 256, NOUT / 256);  // (32, 8) — m fast for XCD locality
    gemm_scan_kernel<<<grid, 512, 131072, stream>>>(xb, wb, bias, alphas, out, carry);
  }
  // 3) self-scanning carry apply, in place on d_out
  scan_apply<<<(BATCH * NCHUNK * NOUT) / 256, 256, 0, stream>>>(out, alphas, carry);
}

// Round 2
// 208.386 us; speedup vs baseline: 1.0703x; 1.0127x over previous
//
#include <hip/hip_runtime.h>
#include <hip/hip_bf16.h>
#include <stdint.h>
#include <stddef.h>

#define D_MODEL 2048
#define NOUT    2048      // SLOTS * D_FIELD
#define BATCH   2
#define SEQ     4096
#define M_TOTAL (BATCH*SEQ)   // 8192
#define SLOTS   8
#define D_FIELD 256
#define CHUNK   32            // carry granularity (matches 2-fragment row pairs)
#define NCHUNK  (SEQ/CHUNK)   // 128
#define NT      (D_MODEL/64)  // 32 K-tiles of BK=64

typedef __attribute__((ext_vector_type(4))) float  floatx4;
typedef __attribute__((ext_vector_type(8))) __bf16 bf16x8;
typedef __attribute__((ext_vector_type(4))) __bf16 bf16x4;

// ---------------------------------------------------------------------------
// async global -> LDS, 16B per lane. LDS dest must be wave-uniform base + lane*16.
__device__ __forceinline__ void async_copy16(const void* gsrc, void* ldst) {
  __builtin_amdgcn_global_load_lds(
      (__attribute__((address_space(1))) const void*)(uintptr_t)gsrc,
      (__attribute__((address_space(3))) void*)(uintptr_t)ldst,
      16, 0, 0);
}

// ---------------------------------------------------------------------------
// Kernel 1: cast x and W fp32 -> bf16 into workspace; also zero barrier ctrs.
__global__ void cast_kernel(const float* __restrict__ x,
                            const float* __restrict__ W,
                            __bf16* __restrict__ xb,
                            __bf16* __restrict__ wb,
                            int* __restrict__ ctr) {
  if (blockIdx.x == 0 && threadIdx.x < 8)
    __hip_atomic_store(&ctr[threadIdx.x], 0, __ATOMIC_RELAXED, __HIP_MEMORY_SCOPE_AGENT);
  const long long nx = (long long)M_TOTAL * D_MODEL;  // 16777216
  const long long nw = (long long)NOUT * D_MODEL;     // 4194304
  long long base = ((long long)blockIdx.x * blockDim.x + threadIdx.x) * 4;
  if (base < nx) {
    float4 v = *(const float4*)(x + base);
    bf16x4 o;
    o[0] = (__bf16)v.x; o[1] = (__bf16)v.y; o[2] = (__bf16)v.z; o[3] = (__bf16)v.w;
    *(bf16x4*)(xb + base) = o;
  } else {
    long long j = base - nx;
    if (j < nw) {
      float4 v = *(const float4*)(W + j);
      bf16x4 o;
      o[0] = (__bf16)v.x; o[1] = (__bf16)v.y; o[2] = (__bf16)v.z; o[3] = (__bf16)v.w;
      *(bf16x4*)(wb + j) = o;
    }
  }
}

// ---------------------------------------------------------------------------
// Kernel 2: 256x256 8-phase GEMM (T2+T3+T4+T5) — UNCHANGED core (R1-verified,
// 66us / 1041 TF) — now with the FULL scan fused into the epilogue:
//   A) raw per-32-chunk carries -> carry buffer (agent-scope atomic stores)
//   B) device barrier over the 32 bx-blocks of this by-slice (atomic ctr;
//      1 block/CU by 128KiB-LDS limit and grid==256 -> all co-resident)
//   C) lane-distributed Horner over LLC-resident carries -> carry-in per chunk;
//      in-register 32-row recurrence (segment prefix via 7 shfls) -> write the
//      FINAL state to d_out. scan_apply kernel deleted: saves the 64MB U
//      read + 64MB rewrite.
// ---------------------------------------------------------------------------
#define VMW4 asm volatile("s_waitcnt vmcnt(4)" ::: "memory")
#define VMW2 asm volatile("s_waitcnt vmcnt(2)" ::: "memory")
#define VMW0 asm volatile("s_waitcnt vmcnt(0)" ::: "memory")
#define LGKM0 do{ asm volatile("s_waitcnt lgkmcnt(0)" ::: "memory"); \
                  __builtin_amdgcn_sched_barrier(0); }while(0)
#define BAR do{ __builtin_amdgcn_s_barrier(); __builtin_amdgcn_sched_barrier(0); }while(0)

#define DSRD(off) (*(const bf16x8*)(smem + (off)))

#define STG(GP, ROFF, DSTOFF, KTN) do{ \
  async_copy16((GP) + (ROFF) + (KTN)*64,      smem + (DSTOFF)); \
  async_copy16((GP) + (ROFF) + (KTN)*64 + 32, smem + (DSTOFF) + 1024); }while(0)

#define RD_AF(BUF, MOFF) do{ \
  _Pragma("unroll") for (int i_ = 0; i_ < 4; ++i_){ \
  _Pragma("unroll") for (int k_ = 0; k_ < 2; ++k_){ \
    afr[i_][k_] = DSRD((BUF)*32768 + ((wM8+(MOFF)+i_)*2+k_)*1024 + fragOff); }} }while(0)

#define RD_BF(BUF, NOFF, DST) do{ \
  _Pragma("unroll") for (int j_ = 0; j_ < 2; ++j_){ \
  _Pragma("unroll") for (int k_ = 0; k_ < 2; ++k_){ \
    DST[j_][k_] = DSRD(65536 + (BUF)*32768 + ((wN4+(NOFF)+j_)*2+k_)*1024 + fragOff); }} }while(0)

#define MFMA_Q(AM, AN, BFR) do{ \
  __builtin_amdgcn_s_setprio(1); \
  _Pragma("unroll") for (int i_ = 0; i_ < 4; ++i_){ \
  _Pragma("unroll") for (int j_ = 0; j_ < 2; ++j_){ \
  _Pragma("unroll") for (int k_ = 0; k_ < 2; ++k_){ \
    acc[(AM)+i_][(AN)+j_] = __builtin_amdgcn_mfma_f32_16x16x32_bf16( \
        afr[i_][k_], BFR[j_][k_], acc[(AM)+i_][(AN)+j_], 0, 0, 0); }}} \
  __builtin_amdgcn_s_setprio(0); }while(0)

#define KTILE(BUF, KTN, DO_STG) do{ \
  /* tp0 */ \
  RD_AF(BUF, 0); \
  RD_BF(BUF, 0, bfr0); \
  if (DO_STG) STG(gA, rA0, ((BUF)^1)*32768 + dA0, KTN); \
  if (DO_STG) { VMW4; } else { VMW2; } \
  BAR; LGKM0; \
  MFMA_Q(0, 0, bfr0); \
  /* tp1 */ \
  RD_BF(BUF, 2, bfr1); \
  if (DO_STG) STG(gB, rB0, ((BUF)^1)*32768 + dB0, KTN); \
  if (DO_STG) { VMW4; } else { VMW0; } \
  BAR; LGKM0; \
  MFMA_Q(0, 2, bfr1); \
  /* tp2 */ \
  RD_AF(BUF, 4); \
  if (DO_STG) STG(gB, rB1, ((BUF)^1)*32768 + dB1, KTN); \
  BAR; LGKM0; \
  MFMA_Q(4, 2, bfr1); \
  /* tp3 */ \
  if (DO_STG) { STG(gA, rA1, ((BUF)^1)*32768 + dA1, KTN); VMW4; } \
  BAR; \
  MFMA_Q(4, 0, bfr0); \
}while(0)

#define CARRY_LD(P) __hip_atomic_load((P), __ATOMIC_RELAXED, __HIP_MEMORY_SCOPE_AGENT)

__global__ __launch_bounds__(512, 2) void gemm_scan_kernel(
    const __bf16* __restrict__ A,    // [M_TOTAL, D_MODEL] bf16
    const __bf16* __restrict__ Bw,   // [NOUT, D_MODEL] bf16
    const float*  __restrict__ bias,
    const float*  __restrict__ alphas,
    float* __restrict__ C,           // [M_TOTAL, NOUT]  -> FINAL state
    float* __restrict__ carry,       // [BATCH, NCHUNK, NOUT] raw chunk carries
    int*   __restrict__ ctr) {       // [8] per-by barrier counters
  extern __shared__ __align__(16) char smem[];
  const int t    = threadIdx.x;
  const int lane = t & 63;
  const int w    = t >> 6;        // wave 0..7
  const int wM   = w >> 2;        // 0..1
  const int wN   = w & 3;         // 0..3
  const int m0   = blockIdx.x * 256;   // m fast -> A-panel's 8 n-blocks on one XCD
  const int n0   = blockIdx.y * 256;

  const int lq = lane >> 4, lr = lane & 15;
  const int fragOff = (lr*64 + lq*16) ^ (((lr >> 3) & 1) << 5);
  const int wM8 = wM*8, wN4 = wN*4;

  // staging: lane -> (row l>>2, pre-swizzled colOff) inside a 16x32 subtile
  const int lrow = lane >> 2;
  const int lcol = ((lane & 3) * 8) ^ ((lane >> 5) * 16);
  const int srA0 = (w & 3) + ((w >> 2) << 3), srA1 = srA0 + 4;
  const int srB0 = (w & 1) + ((w >> 1) << 2), srB1 = srB0 + 2;
  const __bf16* gA = A  + (size_t)m0 * D_MODEL + lcol;
  const __bf16* gB = Bw + (size_t)n0 * D_MODEL + lcol;
  const int rA0 = (srA0*16 + lrow) * D_MODEL;
  const int rA1 = (srA1*16 + lrow) * D_MODEL;
  const int rB0 = (srB0*16 + lrow) * D_MODEL;
  const int rB1 = (srB1*16 + lrow) * D_MODEL;
  const int dA0 = srA0*2048 + lane*16;
  const int dA1 = srA1*2048 + lane*16;
  const int dB0 = 65536 + srB0*2048 + lane*16;
  const int dB1 = 65536 + srB1*2048 + lane*16;

  floatx4 acc[8][4] = {};
  bf16x8 afr[4][2], bfr0[2][2], bfr1[2][2];

  STG(gA, rA0, dA0, 0);
  STG(gB, rB0, dB0, 0);
  STG(gB, rB1, dB1, 0);
  STG(gA, rA1, dA1, 0);
  VMW4;
  BAR;

#pragma unroll 1
  for (int p = 0; p < 15; ++p) {
    KTILE(0, 2*p+1, true);
    KTILE(1, 2*p+2, true);
  }
  KTILE(0, 31, true);
  KTILE(1, 0, false);

  // ======================= fused scan epilogue =============================
  const int mW0 = m0 + wM*128;
  const int nW0 = n0 + wN*64;
  const float alpha = alphas[nW0 >> 8];
  const float a2 = alpha*alpha, a4 = a2*a2, a8 = a4*a4, a16 = a8*a8, a32 = a16*a16;
  float aq = 1.f;                      // alpha^(12-4lq)
#pragma unroll
  for (int i = 0; i < 3; ++i) if (i < 3 - lq) aq *= a4;
  float a4p = 1.f;                     // alpha^(4*lq)
#pragma unroll
  for (int i = 0; i < 3; ++i) if (i < lq) a4p *= a4;
  const int bb  = mW0 >> 12;           // batch
  const int j0w = (mW0 & (SEQ - 1)) >> 5;  // wave's first 32-chunk (wave-uniform)
  float* cbase = carry + (size_t)bb * NCHUNK * NOUT;

  // ---- A) raw chunk carries: rc[j] = sum_{row<32} alpha^(31-row) u_row ----
  float bvv[4], tmv[4][8];
#pragma unroll
  for (int nf = 0; nf < 4; ++nf) {
    const int n = nW0 + nf*16 + lr;
    bvv[nf] = bias[n];
    const float bv = bvv[nf];
#pragma unroll
    for (int mf = 0; mf < 8; ++mf) {
      const floatx4 av = acc[mf][nf];
      tmv[nf][mf] = (((av[0]+bv)*alpha + (av[1]+bv))*alpha + (av[2]+bv))*alpha + (av[3]+bv);
    }
#pragma unroll
    for (int c = 0; c < 4; ++c) {
      float s = (tmv[nf][2*c]*a16 + tmv[nf][2*c+1]) * aq;
      s += __shfl_xor(s, 16, 64);
      s += __shfl_xor(s, 32, 64);
      if (lq == 0)
        __hip_atomic_store(&cbase[(size_t)(j0w + c)*NOUT + n], s,
                           __ATOMIC_RELAXED, __HIP_MEMORY_SCOPE_AGENT);
    }
  }

  // ---- B) device barrier across the 32 bx-blocks of this by-slice ----
  __syncthreads();
  if (t == 0) {
    __hip_atomic_fetch_add(&ctr[blockIdx.y], 1, __ATOMIC_ACQ_REL, __HIP_MEMORY_SCOPE_AGENT);
    while (__hip_atomic_load(&ctr[blockIdx.y], __ATOMIC_ACQUIRE, __HIP_MEMORY_SCOPE_AGENT) < 32)
      __builtin_amdgcn_s_sleep(2);
  }
  __syncthreads();

  // ---- C) prefix carry-in + in-register apply, write final state ----
  // lane scans col (nW0 + lq*16 + lr): all 64 wave cols covered once.
  {
    const float* cbl = cbase + (nW0 + lq*16 + lr);
    float H = 0.f;
#pragma unroll 4
    for (int jp = 0; jp < j0w; ++jp)
      H = a32*H + CARRY_LD(&cbl[(size_t)jp*NOUT]);
    float s0[4];
#pragma unroll
    for (int nf = 0; nf < 4; ++nf) s0[nf] = __shfl(H, nf*16 + lr, 64);

#pragma unroll
    for (int nf = 0; nf < 4; ++nf) {
      const int n = nW0 + nf*16 + lr;
      const float bv = bvv[nf];
      float sp = s0[nf];               // carry-in to chunk j0w (state after prev chunk)
#pragma unroll
      for (int c = 0; c < 4; ++c) {
        if (c > 0)
          sp = a32*sp + CARRY_LD(&cbase[(size_t)(j0w + c - 1)*NOUT + n]);
        float ulo[4], uhi[4];
#pragma unroll
        for (int i = 0; i < 4; ++i) {
          ulo[i] = acc[2*c][nf][i]   + bv;
          uhi[i] = acc[2*c+1][nf][i] + bv;
        }
        const float Tlo = tmv[nf][2*c];
        const float Thi = tmv[nf][2*c+1];
        // gather segment totals across lq groups (segment k lives in lane k*16+lr)
        const float t0  = __shfl(Tlo, lr,      64);
        const float t1  = __shfl(Tlo, 16 + lr, 64);
        const float t2  = __shfl(Tlo, 32 + lr, 64);
        const float t3  = __shfl(Tlo, 48 + lr, 64);
        const float th0 = __shfl(Thi, lr,      64);
        const float th1 = __shfl(Thi, 16 + lr, 64);
        const float th2 = __shfl(Thi, 32 + lr, 64);
        // inbound state to this lane's lo-segment: S = a4^lq * sp + Horner_{k<lq}(t)
        float h = 0.f;
        if (lq > 0) h = t0;
        if (lq > 1) h = h*a4 + t1;
        if (lq > 2) h = h*a4 + t2;
        float Slo = a4p*sp + h;
        // state after row 15 of the chunk
        const float smid = (((t0*a4 + t1)*a4 + t2)*a4 + t3) + a16*sp;
        float hh = 0.f;
        if (lq > 0) hh = th0;
        if (lq > 1) hh = hh*a4 + th1;
        if (lq > 2) hh = hh*a4 + th2;
        float Shi = a4p*smid + hh;
        // apply 4-row recurrences and store final state
        const size_t rowb = (size_t)(mW0 + 2*c*16 + lq*4);
        float s = Slo;
#pragma unroll
        for (int i = 0; i < 4; ++i) { s = alpha*s + ulo[i]; C[(rowb + i)*NOUT + n] = s; }
        s = Shi;
#pragma unroll
        for (int i = 0; i < 4; ++i) { s = alpha*s + uhi[i]; C[(rowb + 16 + i)*NOUT + n] = s; }
      }
    }
  }
}

// ---------------------------------------------------------------------------
extern "C" void kernel_launch(void* const* d_in, const int* in_sizes, int n_in,
                              void* d_out, int out_size, void* d_ws, size_t ws_size,
                              hipStream_t stream) {
  const float* x      = (const float*)d_in[0];
  const float* W      = (const float*)d_in[1];
  const float* bias   = (const float*)d_in[2];
  const float* alphas = (const float*)d_in[3];
  float* out = (float*)d_out;

  // workspace: xb 33,554,432 | wb 8,388,608 | carry 2,097,152 | ctr 32B
  __bf16* xb   = (__bf16*)d_ws;
  __bf16* wb   = (__bf16*)((char*)d_ws + (size_t)M_TOTAL * D_MODEL * 2);
  float* carry = (float*)((char*)d_ws + (size_t)M_TOTAL * D_MODEL * 2
                                       + (size_t)NOUT * D_MODEL * 2);
  int* ctr     = (int*)((char*)d_ws + (size_t)M_TOTAL * D_MODEL * 2
                                     + (size_t)NOUT * D_MODEL * 2
                                     + (size_t)BATCH * NCHUNK * NOUT * 4);

  // 1) cast fp32 -> bf16 (+ zero barrier counters)
  {
    const long long total = ((long long)M_TOTAL * D_MODEL + (long long)NOUT * D_MODEL) / 4;
    const int blocks = (int)((total + 255) / 256);  // 20480
    cast_kernel<<<blocks, 256, 0, stream>>>(x, W, xb, wb, ctr);
  }
  // 2) GEMM + fused full scan -> d_out holds final state. grid MUST stay 256
  //    blocks (1/CU via 128KiB LDS) for the device-barrier co-residency.
  {
    dim3 grid(M_TOTAL / 256, NOUT / 256);  // (32, 8)
    gemm_scan_kernel<<<grid, 512, 131072, stream>>>(xb, wb, bias, alphas, out, carry, ctr);
  }
}